// Round 19
// baseline (175.359 us; speedup 1.0000x reference)
//
#include <hip/hip_runtime.h>
#include <cstddef>

// B=4, L=4096 (=64x64), d_model=512, d_inner=512, dt_rank=32, d_state=1
// GEMMs: uniform 1-term bf16, 2-phase double-buffered, BK=32, 128x128,
// 64-row x 128B LDS panels with 3-bit XOR swizzle (conflict-free ds_read).
// gemm0 epilogue: C staged through LDS (XOR-swizzled [row][256B] tile) ->
// 128B-contiguous coalesced global stores for BOTH xin (ch-major) and z
// (px-major) halves — kills the 8B/2B scattered-store write amplification.
// bf16 intermediates: xin, z, ypre/y_t. scan: thread-serial(16)+wave-scan.

typedef __attribute__((ext_vector_type(8))) short short8;
typedef __attribute__((ext_vector_type(8))) unsigned short ushort8_t;
typedef __attribute__((ext_vector_type(4))) float f32x4;

__device__ __forceinline__ void gload16(const void* g, void* l) {
  __builtin_amdgcn_global_load_lds(
      (const __attribute__((address_space(1))) void*)g,
      (__attribute__((address_space(3))) void*)l, 16, 0, 0);
}

__device__ __forceinline__ unsigned short bf16rne(float v) {
  unsigned u = __float_as_uint(v);
  return (unsigned short)((u + 0x7fffu + ((u >> 16) & 1u)) >> 16);
}

__device__ __forceinline__ float b2f(unsigned short u) {
  return __uint_as_float((unsigned)u << 16);
}

// panel layout: 8 KB = 64 LDS-rows x 128B; m-row r lives at LDS-row r>>1,
// half (r&1); byte-in-row swizzled by ((Lr&7)<<4).
__device__ __forceinline__ int lds_read_off(int r, int q16) {
  int Lr = r >> 1;
  return (Lr << 7) + (((((r & 1) << 6) | q16)) ^ ((Lr & 7) << 4));
}

// ------- prep: x -> bf16 (blocks 0..8191); win -> bf16 (8192..8703) ---------
__global__ __launch_bounds__(256)
void prep_k(const float* __restrict__ x, const float* __restrict__ win,
            unsigned short* __restrict__ Ahi, unsigned short* __restrict__ Whi)
{
  int bid = blockIdx.x;
  if (bid < 8192) {
    int i = bid * 256 + threadIdx.x;            // < 2097152
    float4 v = ((const float4*)x)[i];
    ((ushort4*)Ahi)[i] = make_ushort4(bf16rne(v.x), bf16rne(v.y), bf16rne(v.z), bf16rne(v.w));
  } else {
    int i = (bid - 8192) * 256 + threadIdx.x;   // < 131072
    float4 v = ((const float4*)win)[i];
    ((ushort4*)Whi)[i] = make_ushort4(bf16rne(v.x), bf16rne(v.y), bf16rne(v.z), bf16rne(v.w));
  }
}

// ---------------- fp32 -> bf16 RNE ------------------------------------------
__global__ __launch_bounds__(256)
void cvt_hi_k(const float* __restrict__ in, unsigned short* __restrict__ hi, int n4)
{
  int i = blockIdx.x * 256 + threadIdx.x;
  if (i >= n4) return;
  float4 v = ((const float4*)in)[i];
  ((ushort4*)hi)[i] = make_ushort4(bf16rne(v.x), bf16rne(v.y), bf16rne(v.z), bf16rne(v.w));
}

// ---------------- gemm0: 128x128, BK=32, 2-phase dbuf, dual bf16 out --------
__global__ __launch_bounds__(256)
void gemm0_k(const unsigned short* __restrict__ Ahi, const unsigned short* __restrict__ Whi,
             unsigned short* __restrict__ xinb, unsigned short* __restrict__ zb16)
{
  __shared__ char smem[32768];     // 2 bufs x {A 8K | B 8K}; epilogue C tile
  const int tid = threadIdx.x;
  const int wave = tid >> 6, lane = tid & 63;

  const int nwg = gridDim.x;       // 1024
  const int q = nwg >> 3, r = nwg & 7;
  const int xcd = blockIdx.x & 7, wi = blockIdx.x >> 3;
  const int logical = (xcd < r ? xcd * (q + 1) : r * (q + 1) + (xcd - r) * q) + wi;
  const int tm = logical >> 3, tn = logical & 7;
  const int m0 = tm << 7, n0 = tn << 7;

  const int wm = (wave & 1) << 6;
  const int wn = (wave >> 1) << 6;
  const int q16 = (lane >> 4) << 4;
  const int l15 = lane & 15;

  // staging: linear dest o; source = inverse-swizzled (row, kbyte)
  int srow[2], scol[2];
#pragma unroll
  for (int c = 0; c < 2; ++c) {
    int o = (wave << 11) + (c << 10) + (lane << 4);
    int Lr = o >> 7;
    int ub = (o & 127) ^ ((Lr & 7) << 4);
    srow[c] = (Lr << 1) + (ub >> 6);
    scol[c] = ub & 63;
  }

  f32x4 acc[4][4];
#pragma unroll
  for (int i = 0; i < 4; ++i)
#pragma unroll
    for (int j = 0; j < 4; ++j) acc[i][j] = (f32x4){0.f, 0.f, 0.f, 0.f};

  const char* Ag = (const char*)Ahi;
  const char* Bg = (const char*)Whi;

#define G0_STAGE(buf, kt)                                                     \
  {                                                                           \
    char* base_ = smem + (buf) * 16384;                                       \
    int kb_ = (kt) << 6;                                                      \
    _Pragma("unroll")                                                         \
    for (int c = 0; c < 2; ++c) {                                             \
      int lo_ = (wave << 11) + (c << 10);                                     \
      gload16(Ag + (size_t)(m0 + srow[c]) * 1024 + kb_ + scol[c], base_ + lo_);       \
      gload16(Bg + (size_t)(n0 + srow[c]) * 1024 + kb_ + scol[c], base_ + 8192 + lo_);\
    }                                                                         \
  }

  G0_STAGE(0, 0);
  __syncthreads();
  for (int kt = 0; kt < 16; ++kt) {
    int cur = kt & 1;
    if (kt < 15) G0_STAGE(cur ^ 1, kt + 1);
    const char* bp = smem + cur * 16384;
    short8 af[4], bh[4];
#pragma unroll
    for (int i = 0; i < 4; ++i)
      af[i] = *(const short8*)(bp + lds_read_off(wm + (i << 4) + l15, q16));
#pragma unroll
    for (int j = 0; j < 4; ++j)
      bh[j] = *(const short8*)(bp + 8192 + lds_read_off(wn + (j << 4) + l15, q16));
#pragma unroll
    for (int i = 0; i < 4; ++i)
#pragma unroll
      for (int j = 0; j < 4; ++j)
        acc[i][j] = __builtin_amdgcn_mfma_f32_16x16x32_bf16(af[i], bh[j], acc[i][j], 0, 0, 0);
    __syncthreads();
  }
#undef G0_STAGE

  // ---- epilogue through LDS: [row][256B] tile, slot XOR (row&7)<<4 ----
  char* sT = smem;                 // 128 rows x 256B = 32 KB (reads done)
  if (n0 < 512) {
    // xin (ch-major): LDS row = n_local, data along m
#pragma unroll
    for (int j = 0; j < 4; ++j) {
      int nl = wn + (j << 4) + l15;
#pragma unroll
      for (int i = 0; i < 4; ++i) {
        int ml = wm + (i << 4) + ((lane >> 4) << 2);
        int byte = nl * 256 + ((ml << 1) ^ ((nl & 7) << 4));
        ushort4 hv = make_ushort4(bf16rne(acc[i][j][0]), bf16rne(acc[i][j][1]),
                                  bf16rne(acc[i][j][2]), bf16rne(acc[i][j][3]));
        *(ushort4*)(sT + byte) = hv;
      }
    }
    __syncthreads();
    int rowl = tid >> 1, half = tid & 1;
    int b = m0 >> 12, lb = (m0 & 4095) + (half << 6);
    unsigned short* dst = &xinb[((size_t)(b * 512 + n0 + rowl) << 12) + lb];
#pragma unroll
    for (int c = 0; c < 8; ++c) {
      int m = (half << 6) + (c << 3);
      int byte = rowl * 256 + ((m << 1) ^ ((rowl & 7) << 4));
      *(ushort8_t*)&dst[c * 8] = *(ushort8_t*)(sT + byte);
    }
  } else {
    // z (px-major): LDS row = m_local, data along n
#pragma unroll
    for (int j = 0; j < 4; ++j) {
      int nl = wn + (j << 4) + l15;
#pragma unroll
      for (int i = 0; i < 4; ++i) {
        int mlb = wm + (i << 4) + ((lane >> 4) << 2);
#pragma unroll
        for (int rr = 0; rr < 4; ++rr) {
          int ml = mlb + rr;
          int byte = ml * 256 + ((nl << 1) ^ ((ml & 7) << 4));
          *(unsigned short*)(sT + byte) = bf16rne(acc[i][j][rr]);
        }
      }
    }
    __syncthreads();
    int rowl = tid >> 1, half = tid & 1;
    unsigned short* dst = &zb16[(size_t)(m0 + rowl) * 512 + (n0 - 512) + (half << 6)];
#pragma unroll
    for (int c = 0; c < 8; ++c) {
      int n = (half << 6) + (c << 3);
      int byte = rowl * 256 + ((n << 1) ^ ((rowl & 7) << 4));
      *(ushort8_t*)&dst[c * 8] = *(ushort8_t*)(sT + byte);
    }
  }
}

// ---------------- gemm1: 128x128, BK=32, 2-phase dbuf, 1-term, fp32 out -----
__global__ __launch_bounds__(256)
void gemm1_k(const unsigned short* __restrict__ Ag_, const unsigned short* __restrict__ Whi,
             float* __restrict__ o1)
{
  __shared__ char smem[32768];     // 2 bufs x {A 8K | B 8K}
  const int tid = threadIdx.x;
  const int wave = tid >> 6, lane = tid & 63;

  const int nwg = gridDim.x;       // 512
  const int q = nwg >> 3, r = nwg & 7;
  const int xcd = blockIdx.x & 7, wi = blockIdx.x >> 3;
  const int logical = (xcd < r ? xcd * (q + 1) : r * (q + 1) + (xcd - r) * q) + wi;
  const int tm = logical >> 2, tn = logical & 3;
  const int m0 = tm << 7, n0 = tn << 7;

  const int wm = (wave & 1) << 6;
  const int wn = (wave >> 1) << 6;
  const int q16 = (lane >> 4) << 4;
  const int l15 = lane & 15;

  int srow[2], scol[2];
#pragma unroll
  for (int c = 0; c < 2; ++c) {
    int o = (wave << 11) + (c << 10) + (lane << 4);
    int Lr = o >> 7;
    int ub = (o & 127) ^ ((Lr & 7) << 4);
    srow[c] = (Lr << 1) + (ub >> 6);
    scol[c] = ub & 63;
  }

  f32x4 acc[4][4];
#pragma unroll
  for (int i = 0; i < 4; ++i)
#pragma unroll
    for (int j = 0; j < 4; ++j) acc[i][j] = (f32x4){0.f, 0.f, 0.f, 0.f};

  const char* Ag = (const char*)Ag_;
  const char* Bg = (const char*)Whi;

#define G1_STAGE(buf, kt)                                                     \
  {                                                                           \
    char* base_ = smem + (buf) * 16384;                                       \
    int kb_ = (kt) << 6;                                                      \
    _Pragma("unroll")                                                         \
    for (int c = 0; c < 2; ++c) {                                             \
      int lo_ = (wave << 11) + (c << 10);                                     \
      gload16(Ag + (size_t)(m0 + srow[c]) * 1024 + kb_ + scol[c], base_ + lo_);       \
      gload16(Bg + (size_t)(n0 + srow[c]) * 1024 + kb_ + scol[c], base_ + 8192 + lo_);\
    }                                                                         \
  }

  G1_STAGE(0, 0);
  __syncthreads();
  for (int kt = 0; kt < 16; ++kt) {
    int cur = kt & 1;
    if (kt < 15) G1_STAGE(cur ^ 1, kt + 1);
    const char* bp = smem + cur * 16384;
    short8 af[4], bh[4];
#pragma unroll
    for (int i = 0; i < 4; ++i)
      af[i] = *(const short8*)(bp + lds_read_off(wm + (i << 4) + l15, q16));
#pragma unroll
    for (int j = 0; j < 4; ++j)
      bh[j] = *(const short8*)(bp + 8192 + lds_read_off(wn + (j << 4) + l15, q16));
#pragma unroll
    for (int i = 0; i < 4; ++i)
#pragma unroll
      for (int j = 0; j < 4; ++j)
        acc[i][j] = __builtin_amdgcn_mfma_f32_16x16x32_bf16(af[i], bh[j], acc[i][j], 0, 0, 0);
    __syncthreads();
  }
#undef G1_STAGE

  // stage C tile through LDS in two 64x128 halves; store coalesced float4
  float* sC = (float*)smem;           // 64 x 128 fp32 = 32 KB
  const int i_base = (lane >> 4) << 2;
#pragma unroll
  for (int half = 0; half < 2; ++half) {
    __syncthreads();
    if ((wave & 1) == half) {
#pragma unroll
      for (int j = 0; j < 4; ++j) {
        int nl = wn + (j << 4) + l15;
#pragma unroll
        for (int i = 0; i < 4; ++i) {
          int mloc = (i << 4) + i_base;
#pragma unroll
          for (int rr = 0; rr < 4; ++rr)
            sC[(mloc + rr) * 128 + nl] = acc[i][j][rr];
        }
      }
    }
    __syncthreads();
    int cx = (tid & 31) << 2;
    int r0 = tid >> 5;
#pragma unroll
    for (int it = 0; it < 8; ++it) {
      int row = r0 + (it << 3);
      *(float4*)&o1[(size_t)(m0 + (half << 6) + row) * 512 + n0 + cx] =
          *(float4*)&sC[row * 128 + cx];
    }
  }
}

// -------- depthwise 3x3 SAME (zero pad) + bias + silu, bf16 in, fp32 out ----
__global__ __launch_bounds__(256)
void conv_silu_k(const unsigned short* __restrict__ xin, const float* __restrict__ w,
                 const float* __restrict__ bias, float* __restrict__ xs)
{
  __shared__ float t[64][65];
  int plane = blockIdx.x;          // b*512 + d
  int d = plane & 511;
  int tid = threadIdx.x;
  const unsigned short* src = xin + (size_t)plane * 4096;
  int l0 = tid << 4, row = tid >> 2, c0 = (tid & 3) << 4;
  ushort8_t v0 = *(const ushort8_t*)&src[l0];
  ushort8_t v1 = *(const ushort8_t*)&src[l0 + 8];
#pragma unroll
  for (int j = 0; j < 8; ++j) {
    t[row][c0 + j]     = b2f(v0[j]);
    t[row][c0 + 8 + j] = b2f(v1[j]);
  }
  float wv[9];
#pragma unroll
  for (int j = 0; j < 9; j++) wv[j] = w[d * 9 + j];
  float bv = bias[d];
  __syncthreads();
  float* dst = xs + (size_t)plane * 4096;
#pragma unroll
  for (int i = 0; i < 16; i++) {
    int idx = tid + i * 256;
    int y = idx >> 6, x = idx & 63;
    float s = bv;
#pragma unroll
    for (int u = 0; u < 3; u++)
#pragma unroll
      for (int v = 0; v < 3; v++) {
        int yy = y + u - 1, xx = x + v - 1;
        if (yy >= 0 && yy < 64 && xx >= 0 && xx < 64)
          s = fmaf(wv[u * 3 + v], t[yy][xx], s);
      }
    dst[idx] = s * (1.f / (1.f + __expf(-s)));   // silu
  }
}

// ------- 3a: partial x_dbl GEMM: 8-way split over d; one pixel per thread ---
__global__ __launch_bounds__(256)
void xdbl_part_k(const float* __restrict__ xs, const float* __restrict__ xpw,
                 float* __restrict__ partial)
{
  __shared__ float sw[34 * 64];    // xpw chunk, [k][dd]
  int tid = threadIdx.x;
  int p  = blockIdx.x * 256 + tid;   // pixel 0..16383 (b*4096+l)
  int d0 = blockIdx.y * 64;
  int b = p >> 12, l = p & 4095;
  for (int i = tid; i < 34 * 64; i += 256) {
    int k = i >> 6, dd = i & 63;
    sw[i] = xpw[k * 512 + d0 + dd];
  }
  __syncthreads();
  float acc[34];
#pragma unroll
  for (int k = 0; k < 34; k++) acc[k] = 0.f;
  const float* xp = xs + (size_t)(b * 512 + d0) * 4096 + l;
#pragma unroll 4
  for (int dd = 0; dd < 64; dd++) {
    float v = xp[(size_t)dd * 4096];
#pragma unroll
    for (int k = 0; k < 34; k++) acc[k] = fmaf(sw[k * 64 + dd], v, acc[k]);
  }
  float* op = partial + (size_t)blockIdx.y * 34 * 16384 + p;
#pragma unroll
  for (int k = 0; k < 34; k++) op[(size_t)k * 16384] = acc[k];
}

// ------- 3b: reduce 8 partials -> xdbl_r[34][16384] -------------------------
__global__ __launch_bounds__(256)
void xdbl_reduce_k(const float* __restrict__ partial, float* __restrict__ xdbl_r)
{
  int gid = blockIdx.x * 256 + threadIdx.x;   // 0 .. 34*16384-1
  float s = 0.f;
#pragma unroll
  for (int sp = 0; sp < 8; sp++) s += partial[(size_t)sp * 34 * 16384 + gid];
  xdbl_r[gid] = s;
}

// ------- 3c: dts -> softplus -> delta only ----------------------------------
__global__ __launch_bounds__(256)
void delta_k(const float* __restrict__ xdbl_r, const float* __restrict__ dtw,
             const float* __restrict__ dtb, float* __restrict__ del)
{
  __shared__ float sm[32][256];    // dt-rank rows
  int tid = threadIdx.x;
  int l0 = blockIdx.x * 256;       // l tile within batch
  int d0 = blockIdx.y * 64;        // d chunk
  int b  = blockIdx.z;
  int p0 = b * 4096 + l0;
#pragma unroll
  for (int k = 0; k < 32; k++) sm[k][tid] = xdbl_r[k * 16384 + p0 + tid];
  __syncthreads();
#pragma unroll 2
  for (int dd = 0; dd < 64; dd++) {
    int d = d0 + dd;
    float s = dtb[d];
#pragma unroll
    for (int r = 0; r < 32; r++) s = fmaf(dtw[d * 32 + r], sm[r][tid], s);
    float delta = fmaxf(s, 0.f) + __logf(1.f + __expf(-fabsf(s)));  // softplus
    del[((size_t)(b * 512 + d) << 12) + l0 + tid] = delta;
  }
}

// ---- fused: a/bb on-the-fly + thread-serial(16)+wave scan + dilated convs --
__global__ __launch_bounds__(256)
void scan_sfconv_k(const float* __restrict__ del, const float* __restrict__ Bsr,
                   const float* __restrict__ xs, const float* __restrict__ A_logs,
                   const float* __restrict__ k1, const float* __restrict__ k2,
                   const float* __restrict__ k3, const float* __restrict__ alpha,
                   const float* __restrict__ Cs, const float* __restrict__ Ds,
                   unsigned short* __restrict__ ypre)
{
  __shared__ float t[64][65];      // h grid, conv source
  __shared__ float segA[4], segH[4];
  int plane = blockIdx.x;
  int d = plane & 511;
  int b = plane >> 9;
  int tid = threadIdx.x;
  int wave = tid >> 6, lane = tid & 63;
  size_t base = (size_t)plane * 4096;
  float Ad = -__expf(A_logs[d]);

  const int l0 = tid << 4;
  float a_reg[16], b_reg[16], x_reg[16];
#pragma unroll
  for (int k = 0; k < 4; ++k) {
    float4 dv4 = *(const float4*)&del[base + l0 + k * 4];
    float4 bs4 = *(const float4*)&Bsr[(b << 12) + l0 + k * 4];
    float4 xs4 = *(const float4*)&xs[base + l0 + k * 4];
    float dv[4] = {dv4.x, dv4.y, dv4.z, dv4.w};
    float bs[4] = {bs4.x, bs4.y, bs4.z, bs4.w};
    float xv[4] = {xs4.x, xs4.y, xs4.z, xs4.w};
#pragma unroll
    for (int j = 0; j < 4; ++j) {
      a_reg[k * 4 + j] = __expf(dv[j] * Ad);
      b_reg[k * 4 + j] = dv[j] * bs[j] * xv[j];
      x_reg[k * 4 + j] = xv[j];
    }
  }

  float A_th = a_reg[0], H_th = b_reg[0];
#pragma unroll
  for (int j = 1; j < 16; ++j) {
    H_th = fmaf(a_reg[j], H_th, b_reg[j]);
    A_th *= a_reg[j];
  }

#pragma unroll
  for (int off = 1; off < 64; off <<= 1) {
    float Ap = __shfl_up(A_th, off);
    float Hp = __shfl_up(H_th, off);
    if (lane >= off) { H_th = fmaf(A_th, Hp, H_th); A_th *= Ap; }
  }
  float eA = __shfl_up(A_th, 1);
  float eH = __shfl_up(H_th, 1);
  if (lane == 0) { eA = 1.f; eH = 0.f; }
  if (lane == 63) { segA[wave] = A_th; segH[wave] = H_th; }
  __syncthreads();

  float cy1 = segH[0];
  float cy2 = fmaf(segA[1], cy1, segH[1]);
  float cy3 = fmaf(segA[2], cy2, segH[2]);
  float myc = (wave == 1) ? cy1 : (wave == 2) ? cy2 : (wave == 3) ? cy3 : 0.f;
  float h = fmaf(eA, myc, eH);     // h entering this thread's segment

  int row = tid >> 2, c0 = (tid & 3) << 4;
#pragma unroll
  for (int j = 0; j < 16; ++j) {
    h = fmaf(a_reg[j], h, b_reg[j]);
    t[row][c0 + j] = h;
  }
  __syncthreads();

  float wv[3][9];
  float a0 = alpha[0], a1 = alpha[1], a2 = alpha[2];
#pragma unroll
  for (int j = 0; j < 9; j++) {
    wv[0][j] = a0 * k1[d * 9 + j];
    wv[1][j] = a1 * k2[d * 9 + j];
    wv[2][j] = a2 * k3[d * 9 + j];
  }
  float Dv = Ds[d];
  float cs_reg[16];
#pragma unroll
  for (int k = 0; k < 4; ++k) {
    float4 c4 = *(const float4*)&Cs[(b << 12) + l0 + k * 4];
    cs_reg[k * 4 + 0] = c4.x; cs_reg[k * 4 + 1] = c4.y;
    cs_reg[k * 4 + 2] = c4.z; cs_reg[k * 4 + 3] = c4.w;
  }
  unsigned short ov[16];
  const int y = row;               // constant per thread
#pragma unroll
  for (int j = 0; j < 16; j++) {
    int x = c0 + j;
    float s = 0.f;
#pragma unroll
    for (int dil = 1; dil <= 3; dil++)
#pragma unroll
      for (int uu = 0; uu < 3; uu++)
#pragma unroll
        for (int vv = 0; vv < 3; vv++) {
          int yy = y + (uu - 1) * dil; yy = yy < 0 ? 0 : (yy > 63 ? 63 : yy);
          int xx = x + (vv - 1) * dil; xx = xx < 0 ? 0 : (xx > 63 ? 63 : xx);
          s = fmaf(wv[dil - 1][uu * 3 + vv], t[yy][xx], s);
        }
    ov[j] = bf16rne(fmaf(s, cs_reg[j], x_reg[j] * Dv));
  }
  ushort8_t o0, o1;
#pragma unroll
  for (int j = 0; j < 8; ++j) { o0[j] = ov[j]; o1[j] = ov[8 + j]; }
  *(ushort8_t*)&ypre[base + l0]     = o0;
  *(ushort8_t*)&ypre[base + l0 + 8] = o1;
}

// ---------------- bf16 transpose (B,D,L) -> (B,L,D) --------------------------
__global__ __launch_bounds__(256)
void transpose_bf16_k(const unsigned short* __restrict__ src,
                      unsigned short* __restrict__ dst)
{
  __shared__ unsigned short t[64][72];   // [l][d], pad 72
  int l0 = blockIdx.x * 64;
  int d0 = blockIdx.y * 64;
  int b  = blockIdx.z;
  int tid = threadIdx.x;
  int dl = tid & 63, lg0 = tid >> 6;
#pragma unroll
  for (int i = 0; i < 2; ++i) {
    int lg = lg0 + i * 4;                // l-chunk of 8
    ushort8_t v = *(const ushort8_t*)&src[(size_t)(b * 512 + d0 + dl) * 4096 + l0 + lg * 8];
#pragma unroll
    for (int j = 0; j < 8; ++j) t[lg * 8 + j][dl] = v[j];
  }
  __syncthreads();
  int pl = tid >> 2, c0 = (tid & 3) << 4;
  ushort8_t a = *(const ushort8_t*)&t[pl][c0];
  ushort8_t bb = *(const ushort8_t*)&t[pl][c0 + 8];
  size_t o = (size_t)(b * 4096 + l0 + pl) * 512 + d0 + c0;
  *(ushort8_t*)&dst[o] = a;
  *(ushort8_t*)&dst[o + 8] = bb;
}

// -------- LayerNorm over D + silu(z) gate, bf16 in/out ----------------------
__global__ __launch_bounds__(256)
void ln_silu_split_k(const unsigned short* __restrict__ y,
                     const unsigned short* __restrict__ z,
                     const float* __restrict__ lw, const float* __restrict__ lb,
                     unsigned short* __restrict__ hi)
{
  int wid = threadIdx.x >> 6, lane = threadIdx.x & 63;
  int pix = blockIdx.x * 4 + wid;            // 0..16383
  const unsigned short* yp = y + (size_t)pix * 512;
  const unsigned short* zp = z + (size_t)pix * 512;
  ushort8_t yv8 = *(const ushort8_t*)&yp[lane * 8];
  float vv[8];
#pragma unroll
  for (int j = 0; j < 8; j++) vv[j] = b2f(yv8[j]);
  float sum = 0.f;
#pragma unroll
  for (int j = 0; j < 8; j++) sum += vv[j];
#pragma unroll
  for (int off = 1; off < 64; off <<= 1) sum += __shfl_xor(sum, off);
  float mu = sum * (1.f / 512.f);
  float q = 0.f;
#pragma unroll
  for (int j = 0; j < 8; j++) { float dd = vv[j] - mu; q += dd * dd; }
#pragma unroll
  for (int off = 1; off < 64; off <<= 1) q += __shfl_xor(q, off);
  float rstd = rsqrtf(q * (1.f / 512.f) + 1e-5f);
  ushort8_t zv8 = *(const ushort8_t*)&zp[lane * 8];
  unsigned short oh[8];
#pragma unroll
  for (int j = 0; j < 8; j++) {
    int dch = lane * 8 + j;
    float val = (vv[j] - mu) * rstd * lw[dch] + lb[dch];
    float zv = b2f(zv8[j]);
    float ov = val * (zv * (1.f / (1.f + __expf(-zv))));
    oh[j] = bf16rne(ov);
  }
  size_t o = (size_t)pix * 512 + lane * 8;
  *(ushort4*)&hi[o]     = make_ushort4(oh[0], oh[1], oh[2], oh[3]);
  *(ushort4*)&hi[o + 4] = make_ushort4(oh[4], oh[5], oh[6], oh[7]);
}

extern "C" void kernel_launch(void* const* d_in, const int* in_sizes, int n_in,
                              void* d_out, int out_size, void* d_ws, size_t ws_size,
                              hipStream_t stream)
{
  const float* x    = (const float*)d_in[0];
  const float* win  = (const float*)d_in[1];
  const float* cw   = (const float*)d_in[2];
  const float* cb   = (const float*)d_in[3];
  const float* xpw  = (const float*)d_in[4];
  const float* dtw  = (const float*)d_in[5];
  const float* dtb  = (const float*)d_in[6];
  const float* alog = (const float*)d_in[7];
  const float* Dsv  = (const float*)d_in[8];
  const float* k1   = (const float*)d_in[9];
  const float* k2   = (const float*)d_in[10];
  const float* k3   = (const float*)d_in[11];
  const float* alp  = (const float*)d_in[12];
  const float* lw   = (const float*)d_in[13];
  const float* lb   = (const float*)d_in[14];
  const float* wout = (const float*)d_in[15];
  float* out = (float*)d_out;

  const size_t NP = (size_t)4 * 512 * 4096;   // 8,388,608 elems per (B,D,L) buffer
  float* ws = (float*)d_ws;
  float* xs     = ws;                 // Whi -> xs fp32 -> y_t bf16 -> Ohi
  float* zbuf   = ws + NP;            // z bf16 (1st half) | ypre bf16 (2nd half)
  float* w4     = ws + 2 * NP;        // Ahi -> delta -> Yhi
  float* xdbl_r = ws + 3 * NP;        // 34 x 16384

  unsigned short* Ahi  = (unsigned short*)w4;        // 16384x512 bf16
  unsigned short* Whi  = (unsigned short*)xs;        // 1024x512 bf16
  unsigned short* xinb = (unsigned short*)d_out;     // xin bf16 (d_out scratch)
  unsigned short* zb16 = (unsigned short*)zbuf;              // 16384x512 bf16
  unsigned short* yp16 = zb16 + (size_t)16384 * 512;         // ypre bf16
  unsigned short* yt16 = (unsigned short*)xs;        // y_t bf16 (xs dead)
  unsigned short* Yhi  = (unsigned short*)w4;        // after delta consumed
  unsigned short* Ohi  = (unsigned short*)xs;        // after y_t consumed
  float* xsf = xs;                                   // xs fp32 view

  prep_k<<<8704, 256, 0, stream>>>(x, win, Ahi, Whi);                       // x, win -> bf16
  gemm0_k<<<1024, 256, 0, stream>>>(Ahi, Whi, xinb, zb16);                  // xin, z (bf16)
  conv_silu_k<<<2048, 256, 0, stream>>>(xinb, cw, cb, xsf);                 // xs fp32
  xdbl_part_k<<<dim3(64, 8), 256, 0, stream>>>(xsf, xpw, out);              // partial->d_out
  xdbl_reduce_k<<<2176, 256, 0, stream>>>(out, xdbl_r);                     // xdbl_r
  delta_k<<<dim3(16, 8, 4), 256, 0, stream>>>(xdbl_r, dtw, dtb, w4);        // delta->w4
  scan_sfconv_k<<<2048, 256, 0, stream>>>(w4, xdbl_r + 32 * 16384, xsf, alog,
                                          k1, k2, k3, alp,
                                          xdbl_r + 33 * 16384, Dsv, yp16);  // ypre bf16
  transpose_bf16_k<<<dim3(64, 8, 4), 256, 0, stream>>>(yp16, yt16);         // y_t bf16
  ln_silu_split_k<<<4096, 256, 0, stream>>>(yt16, zb16, lw, lb, Yhi);       // y -> bf16
  cvt_hi_k<<<256, 256, 0, stream>>>(wout, Ohi, 65536);                      // wout -> bf16
  gemm1_k<<<512, 256, 0, stream>>>(Yhi, Ohi, out);                          // final 1-term
}

// Round 20
// 170.324 us; speedup vs baseline: 1.0296x; 1.0296x over previous
//
#include <hip/hip_runtime.h>
#include <cstddef>

// B=4, L=4096 (=64x64), d_model=512, d_inner=512, dt_rank=32, d_state=1
// GEMMs: uniform 1-term bf16, 2-phase double-buffered, BK=32, 128x128.
// LDS panels packed as 64 rows x 128B (2 m-rows/LDS-row) with 3-bit XOR
// swizzle ((Lr&7)<<4) -> conflict-free ds_read_b128.
// gemm0: 32 KB LDS (5 blk/CU), dual bf16 out. gemm1: 32 KB LDS, fp32 out.
// bf16 intermediates: xin, z, ypre/y_t. scan: thread-serial(16)+wave-scan.
// (Round-18 configuration restored: best stable measured total.)

typedef __attribute__((ext_vector_type(8))) short short8;
typedef __attribute__((ext_vector_type(8))) unsigned short ushort8_t;
typedef __attribute__((ext_vector_type(4))) float f32x4;

__device__ __forceinline__ void gload16(const void* g, void* l) {
  __builtin_amdgcn_global_load_lds(
      (const __attribute__((address_space(1))) void*)g,
      (__attribute__((address_space(3))) void*)l, 16, 0, 0);
}

__device__ __forceinline__ unsigned short bf16rne(float v) {
  unsigned u = __float_as_uint(v);
  return (unsigned short)((u + 0x7fffu + ((u >> 16) & 1u)) >> 16);
}

__device__ __forceinline__ float b2f(unsigned short u) {
  return __uint_as_float((unsigned)u << 16);
}

// panel layout: 8 KB = 64 LDS-rows x 128B; m-row r lives at LDS-row r>>1,
// half (r&1); byte-in-row swizzled by ((Lr&7)<<4).
__device__ __forceinline__ int lds_read_off(int r, int q16) {
  int Lr = r >> 1;
  return (Lr << 7) + (((((r & 1) << 6) | q16)) ^ ((Lr & 7) << 4));
}

// ------- prep: x -> bf16 (blocks 0..8191); win -> bf16 (8192..8703) ---------
__global__ __launch_bounds__(256)
void prep_k(const float* __restrict__ x, const float* __restrict__ win,
            unsigned short* __restrict__ Ahi, unsigned short* __restrict__ Whi)
{
  int bid = blockIdx.x;
  if (bid < 8192) {
    int i = bid * 256 + threadIdx.x;            // < 2097152
    float4 v = ((const float4*)x)[i];
    ((ushort4*)Ahi)[i] = make_ushort4(bf16rne(v.x), bf16rne(v.y), bf16rne(v.z), bf16rne(v.w));
  } else {
    int i = (bid - 8192) * 256 + threadIdx.x;   // < 131072
    float4 v = ((const float4*)win)[i];
    ((ushort4*)Whi)[i] = make_ushort4(bf16rne(v.x), bf16rne(v.y), bf16rne(v.z), bf16rne(v.w));
  }
}

// ---------------- fp32 -> bf16 RNE ------------------------------------------
__global__ __launch_bounds__(256)
void cvt_hi_k(const float* __restrict__ in, unsigned short* __restrict__ hi, int n4)
{
  int i = blockIdx.x * 256 + threadIdx.x;
  if (i >= n4) return;
  float4 v = ((const float4*)in)[i];
  ((ushort4*)hi)[i] = make_ushort4(bf16rne(v.x), bf16rne(v.y), bf16rne(v.z), bf16rne(v.w));
}

// ---------------- gemm0: 128x128, BK=32, 2-phase dbuf, dual bf16 out --------
__global__ __launch_bounds__(256)
void gemm0_k(const unsigned short* __restrict__ Ahi, const unsigned short* __restrict__ Whi,
             unsigned short* __restrict__ xinb, unsigned short* __restrict__ zb16)
{
  __shared__ char smem[32768];     // 2 bufs x {A 8K | B 8K}
  const int tid = threadIdx.x;
  const int wave = tid >> 6, lane = tid & 63;

  const int nwg = gridDim.x;       // 1024
  const int q = nwg >> 3, r = nwg & 7;
  const int xcd = blockIdx.x & 7, wi = blockIdx.x >> 3;
  const int logical = (xcd < r ? xcd * (q + 1) : r * (q + 1) + (xcd - r) * q) + wi;
  const int tm = logical >> 3, tn = logical & 7;
  const int m0 = tm << 7, n0 = tn << 7;

  const int wm = (wave & 1) << 6;
  const int wn = (wave >> 1) << 6;
  const int q16 = (lane >> 4) << 4;
  const int l15 = lane & 15;

  // staging: linear dest o; source = inverse-swizzled (row, kbyte)
  int srow[2], scol[2];
#pragma unroll
  for (int c = 0; c < 2; ++c) {
    int o = (wave << 11) + (c << 10) + (lane << 4);
    int Lr = o >> 7;
    int ub = (o & 127) ^ ((Lr & 7) << 4);
    srow[c] = (Lr << 1) + (ub >> 6);
    scol[c] = ub & 63;
  }

  f32x4 acc[4][4];
#pragma unroll
  for (int i = 0; i < 4; ++i)
#pragma unroll
    for (int j = 0; j < 4; ++j) acc[i][j] = (f32x4){0.f, 0.f, 0.f, 0.f};

  const char* Ag = (const char*)Ahi;
  const char* Bg = (const char*)Whi;

#define G0_STAGE(buf, kt)                                                     \
  {                                                                           \
    char* base_ = smem + (buf) * 16384;                                       \
    int kb_ = (kt) << 6;                                                      \
    _Pragma("unroll")                                                         \
    for (int c = 0; c < 2; ++c) {                                             \
      int lo_ = (wave << 11) + (c << 10);                                     \
      gload16(Ag + (size_t)(m0 + srow[c]) * 1024 + kb_ + scol[c], base_ + lo_);       \
      gload16(Bg + (size_t)(n0 + srow[c]) * 1024 + kb_ + scol[c], base_ + 8192 + lo_);\
    }                                                                         \
  }

  G0_STAGE(0, 0);
  __syncthreads();
  for (int kt = 0; kt < 16; ++kt) {
    int cur = kt & 1;
    if (kt < 15) G0_STAGE(cur ^ 1, kt + 1);
    const char* bp = smem + cur * 16384;
    short8 af[4], bh[4];
#pragma unroll
    for (int i = 0; i < 4; ++i)
      af[i] = *(const short8*)(bp + lds_read_off(wm + (i << 4) + l15, q16));
#pragma unroll
    for (int j = 0; j < 4; ++j)
      bh[j] = *(const short8*)(bp + 8192 + lds_read_off(wn + (j << 4) + l15, q16));
#pragma unroll
    for (int i = 0; i < 4; ++i)
#pragma unroll
      for (int j = 0; j < 4; ++j)
        acc[i][j] = __builtin_amdgcn_mfma_f32_16x16x32_bf16(af[i], bh[j], acc[i][j], 0, 0, 0);
    __syncthreads();
  }
#undef G0_STAGE

  const int mb_base = m0 + wm + ((lane >> 4) << 2);
#pragma unroll
  for (int j = 0; j < 4; ++j) {
    int n = n0 + wn + (j << 4) + l15;
#pragma unroll
    for (int i = 0; i < 4; ++i) {
      int mb = mb_base + (i << 4);
      if (n < 512) {
        int b = mb >> 12, l = mb & 4095;
        ushort4 hv = make_ushort4(bf16rne(acc[i][j][0]), bf16rne(acc[i][j][1]),
                                  bf16rne(acc[i][j][2]), bf16rne(acc[i][j][3]));
        *(ushort4*)&xinb[((size_t)(b * 512 + n) << 12) + l] = hv;
      } else {
#pragma unroll
        for (int rr = 0; rr < 4; ++rr)
          zb16[(size_t)(mb + rr) * 512 + (n - 512)] = bf16rne(acc[i][j][rr]);
      }
    }
  }
}

// ---------------- gemm1: 128x128, BK=32, 2-phase dbuf, 1-term, fp32 out -----
__global__ __launch_bounds__(256)
void gemm1_k(const unsigned short* __restrict__ Ag_, const unsigned short* __restrict__ Whi,
             float* __restrict__ o1)
{
  __shared__ char smem[32768];     // 2 bufs x {A 8K | B 8K}
  const int tid = threadIdx.x;
  const int wave = tid >> 6, lane = tid & 63;

  const int nwg = gridDim.x;       // 512
  const int q = nwg >> 3, r = nwg & 7;
  const int xcd = blockIdx.x & 7, wi = blockIdx.x >> 3;
  const int logical = (xcd < r ? xcd * (q + 1) : r * (q + 1) + (xcd - r) * q) + wi;
  const int tm = logical >> 2, tn = logical & 3;
  const int m0 = tm << 7, n0 = tn << 7;

  const int wm = (wave & 1) << 6;
  const int wn = (wave >> 1) << 6;
  const int q16 = (lane >> 4) << 4;
  const int l15 = lane & 15;

  int srow[2], scol[2];
#pragma unroll
  for (int c = 0; c < 2; ++c) {
    int o = (wave << 11) + (c << 10) + (lane << 4);
    int Lr = o >> 7;
    int ub = (o & 127) ^ ((Lr & 7) << 4);
    srow[c] = (Lr << 1) + (ub >> 6);
    scol[c] = ub & 63;
  }

  f32x4 acc[4][4];
#pragma unroll
  for (int i = 0; i < 4; ++i)
#pragma unroll
    for (int j = 0; j < 4; ++j) acc[i][j] = (f32x4){0.f, 0.f, 0.f, 0.f};

  const char* Ag = (const char*)Ag_;
  const char* Bg = (const char*)Whi;

#define G1_STAGE(buf, kt)                                                     \
  {                                                                           \
    char* base_ = smem + (buf) * 16384;                                       \
    int kb_ = (kt) << 6;                                                      \
    _Pragma("unroll")                                                         \
    for (int c = 0; c < 2; ++c) {                                             \
      int lo_ = (wave << 11) + (c << 10);                                     \
      gload16(Ag + (size_t)(m0 + srow[c]) * 1024 + kb_ + scol[c], base_ + lo_);       \
      gload16(Bg + (size_t)(n0 + srow[c]) * 1024 + kb_ + scol[c], base_ + 8192 + lo_);\
    }                                                                         \
  }

  G1_STAGE(0, 0);
  __syncthreads();
  for (int kt = 0; kt < 16; ++kt) {
    int cur = kt & 1;
    if (kt < 15) G1_STAGE(cur ^ 1, kt + 1);
    const char* bp = smem + cur * 16384;
    short8 af[4], bh[4];
#pragma unroll
    for (int i = 0; i < 4; ++i)
      af[i] = *(const short8*)(bp + lds_read_off(wm + (i << 4) + l15, q16));
#pragma unroll
    for (int j = 0; j < 4; ++j)
      bh[j] = *(const short8*)(bp + 8192 + lds_read_off(wn + (j << 4) + l15, q16));
#pragma unroll
    for (int i = 0; i < 4; ++i)
#pragma unroll
      for (int j = 0; j < 4; ++j)
        acc[i][j] = __builtin_amdgcn_mfma_f32_16x16x32_bf16(af[i], bh[j], acc[i][j], 0, 0, 0);
    __syncthreads();
  }
#undef G1_STAGE

  // stage C tile through LDS in two 64x128 halves; store coalesced float4
  float* sC = (float*)smem;           // 64 x 128 fp32 = 32 KB
  const int i_base = (lane >> 4) << 2;
#pragma unroll
  for (int half = 0; half < 2; ++half) {
    __syncthreads();
    if ((wave & 1) == half) {
#pragma unroll
      for (int j = 0; j < 4; ++j) {
        int nl = wn + (j << 4) + l15;
#pragma unroll
        for (int i = 0; i < 4; ++i) {
          int mloc = (i << 4) + i_base;
#pragma unroll
          for (int rr = 0; rr < 4; ++rr)
            sC[(mloc + rr) * 128 + nl] = acc[i][j][rr];
        }
      }
    }
    __syncthreads();
    int cx = (tid & 31) << 2;
    int r0 = tid >> 5;
#pragma unroll
    for (int it = 0; it < 8; ++it) {
      int row = r0 + (it << 3);
      *(float4*)&o1[(size_t)(m0 + (half << 6) + row) * 512 + n0 + cx] =
          *(float4*)&sC[row * 128 + cx];
    }
  }
}

// -------- depthwise 3x3 SAME (zero pad) + bias + silu, bf16 in, fp32 out ----
__global__ __launch_bounds__(256)
void conv_silu_k(const unsigned short* __restrict__ xin, const float* __restrict__ w,
                 const float* __restrict__ bias, float* __restrict__ xs)
{
  __shared__ float t[64][65];
  int plane = blockIdx.x;          // b*512 + d
  int d = plane & 511;
  int tid = threadIdx.x;
  const unsigned short* src = xin + (size_t)plane * 4096;
  int l0 = tid << 4, row = tid >> 2, c0 = (tid & 3) << 4;
  ushort8_t v0 = *(const ushort8_t*)&src[l0];
  ushort8_t v1 = *(const ushort8_t*)&src[l0 + 8];
#pragma unroll
  for (int j = 0; j < 8; ++j) {
    t[row][c0 + j]     = b2f(v0[j]);
    t[row][c0 + 8 + j] = b2f(v1[j]);
  }
  float wv[9];
#pragma unroll
  for (int j = 0; j < 9; j++) wv[j] = w[d * 9 + j];
  float bv = bias[d];
  __syncthreads();
  float* dst = xs + (size_t)plane * 4096;
#pragma unroll
  for (int i = 0; i < 16; i++) {
    int idx = tid + i * 256;
    int y = idx >> 6, x = idx & 63;
    float s = bv;
#pragma unroll
    for (int u = 0; u < 3; u++)
#pragma unroll
      for (int v = 0; v < 3; v++) {
        int yy = y + u - 1, xx = x + v - 1;
        if (yy >= 0 && yy < 64 && xx >= 0 && xx < 64)
          s = fmaf(wv[u * 3 + v], t[yy][xx], s);
      }
    dst[idx] = s * (1.f / (1.f + __expf(-s)));   // silu
  }
}

// ------- 3a: partial x_dbl GEMM: 8-way split over d; one pixel per thread ---
__global__ __launch_bounds__(256)
void xdbl_part_k(const float* __restrict__ xs, const float* __restrict__ xpw,
                 float* __restrict__ partial)
{
  __shared__ float sw[34 * 64];    // xpw chunk, [k][dd]
  int tid = threadIdx.x;
  int p  = blockIdx.x * 256 + tid;   // pixel 0..16383 (b*4096+l)
  int d0 = blockIdx.y * 64;
  int b = p >> 12, l = p & 4095;
  for (int i = tid; i < 34 * 64; i += 256) {
    int k = i >> 6, dd = i & 63;
    sw[i] = xpw[k * 512 + d0 + dd];
  }
  __syncthreads();
  float acc[34];
#pragma unroll
  for (int k = 0; k < 34; k++) acc[k] = 0.f;
  const float* xp = xs + (size_t)(b * 512 + d0) * 4096 + l;
#pragma unroll 4
  for (int dd = 0; dd < 64; dd++) {
    float v = xp[(size_t)dd * 4096];
#pragma unroll
    for (int k = 0; k < 34; k++) acc[k] = fmaf(sw[k * 64 + dd], v, acc[k]);
  }
  float* op = partial + (size_t)blockIdx.y * 34 * 16384 + p;
#pragma unroll
  for (int k = 0; k < 34; k++) op[(size_t)k * 16384] = acc[k];
}

// ------- 3b: reduce 8 partials -> xdbl_r[34][16384] -------------------------
__global__ __launch_bounds__(256)
void xdbl_reduce_k(const float* __restrict__ partial, float* __restrict__ xdbl_r)
{
  int gid = blockIdx.x * 256 + threadIdx.x;   // 0 .. 34*16384-1
  float s = 0.f;
#pragma unroll
  for (int sp = 0; sp < 8; sp++) s += partial[(size_t)sp * 34 * 16384 + gid];
  xdbl_r[gid] = s;
}

// ------- 3c: dts -> softplus -> delta only ----------------------------------
__global__ __launch_bounds__(256)
void delta_k(const float* __restrict__ xdbl_r, const float* __restrict__ dtw,
             const float* __restrict__ dtb, float* __restrict__ del)
{
  __shared__ float sm[32][256];    // dt-rank rows
  int tid = threadIdx.x;
  int l0 = blockIdx.x * 256;       // l tile within batch
  int d0 = blockIdx.y * 64;        // d chunk
  int b  = blockIdx.z;
  int p0 = b * 4096 + l0;
#pragma unroll
  for (int k = 0; k < 32; k++) sm[k][tid] = xdbl_r[k * 16384 + p0 + tid];
  __syncthreads();
#pragma unroll 2
  for (int dd = 0; dd < 64; dd++) {
    int d = d0 + dd;
    float s = dtb[d];
#pragma unroll
    for (int r = 0; r < 32; r++) s = fmaf(dtw[d * 32 + r], sm[r][tid], s);
    float delta = fmaxf(s, 0.f) + __logf(1.f + __expf(-fabsf(s)));  // softplus
    del[((size_t)(b * 512 + d) << 12) + l0 + tid] = delta;
  }
}

// ---- fused: a/bb on-the-fly + thread-serial(16)+wave scan + dilated convs --
__global__ __launch_bounds__(256)
void scan_sfconv_k(const float* __restrict__ del, const float* __restrict__ Bsr,
                   const float* __restrict__ xs, const float* __restrict__ A_logs,
                   const float* __restrict__ k1, const float* __restrict__ k2,
                   const float* __restrict__ k3, const float* __restrict__ alpha,
                   const float* __restrict__ Cs, const float* __restrict__ Ds,
                   unsigned short* __restrict__ ypre)
{
  __shared__ float t[64][65];      // h grid, conv source
  __shared__ float segA[4], segH[4];
  int plane = blockIdx.x;
  int d = plane & 511;
  int b = plane >> 9;
  int tid = threadIdx.x;
  int wave = tid >> 6, lane = tid & 63;
  size_t base = (size_t)plane * 4096;
  float Ad = -__expf(A_logs[d]);

  const int l0 = tid << 4;
  float a_reg[16], b_reg[16], x_reg[16];
#pragma unroll
  for (int k = 0; k < 4; ++k) {
    float4 dv4 = *(const float4*)&del[base + l0 + k * 4];
    float4 bs4 = *(const float4*)&Bsr[(b << 12) + l0 + k * 4];
    float4 xs4 = *(const float4*)&xs[base + l0 + k * 4];
    float dv[4] = {dv4.x, dv4.y, dv4.z, dv4.w};
    float bs[4] = {bs4.x, bs4.y, bs4.z, bs4.w};
    float xv[4] = {xs4.x, xs4.y, xs4.z, xs4.w};
#pragma unroll
    for (int j = 0; j < 4; ++j) {
      a_reg[k * 4 + j] = __expf(dv[j] * Ad);
      b_reg[k * 4 + j] = dv[j] * bs[j] * xv[j];
      x_reg[k * 4 + j] = xv[j];
    }
  }

  float A_th = a_reg[0], H_th = b_reg[0];
#pragma unroll
  for (int j = 1; j < 16; ++j) {
    H_th = fmaf(a_reg[j], H_th, b_reg[j]);
    A_th *= a_reg[j];
  }

#pragma unroll
  for (int off = 1; off < 64; off <<= 1) {
    float Ap = __shfl_up(A_th, off);
    float Hp = __shfl_up(H_th, off);
    if (lane >= off) { H_th = fmaf(A_th, Hp, H_th); A_th *= Ap; }
  }
  float eA = __shfl_up(A_th, 1);
  float eH = __shfl_up(H_th, 1);
  if (lane == 0) { eA = 1.f; eH = 0.f; }
  if (lane == 63) { segA[wave] = A_th; segH[wave] = H_th; }
  __syncthreads();

  float cy1 = segH[0];
  float cy2 = fmaf(segA[1], cy1, segH[1]);
  float cy3 = fmaf(segA[2], cy2, segH[2]);
  float myc = (wave == 1) ? cy1 : (wave == 2) ? cy2 : (wave == 3) ? cy3 : 0.f;
  float h = fmaf(eA, myc, eH);     // h entering this thread's segment

  int row = tid >> 2, c0 = (tid & 3) << 4;
#pragma unroll
  for (int j = 0; j < 16; ++j) {
    h = fmaf(a_reg[j], h, b_reg[j]);
    t[row][c0 + j] = h;
  }
  __syncthreads();

  float wv[3][9];
  float a0 = alpha[0], a1 = alpha[1], a2 = alpha[2];
#pragma unroll
  for (int j = 0; j < 9; j++) {
    wv[0][j] = a0 * k1[d * 9 + j];
    wv[1][j] = a1 * k2[d * 9 + j];
    wv[2][j] = a2 * k3[d * 9 + j];
  }
  float Dv = Ds[d];
  float cs_reg[16];
#pragma unroll
  for (int k = 0; k < 4; ++k) {
    float4 c4 = *(const float4*)&Cs[(b << 12) + l0 + k * 4];
    cs_reg[k * 4 + 0] = c4.x; cs_reg[k * 4 + 1] = c4.y;
    cs_reg[k * 4 + 2] = c4.z; cs_reg[k * 4 + 3] = c4.w;
  }
  unsigned short ov[16];
  const int y = row;               // constant per thread
#pragma unroll
  for (int j = 0; j < 16; j++) {
    int x = c0 + j;
    float s = 0.f;
#pragma unroll
    for (int dil = 1; dil <= 3; dil++)
#pragma unroll
      for (int uu = 0; uu < 3; uu++)
#pragma unroll
        for (int vv = 0; vv < 3; vv++) {
          int yy = y + (uu - 1) * dil; yy = yy < 0 ? 0 : (yy > 63 ? 63 : yy);
          int xx = x + (vv - 1) * dil; xx = xx < 0 ? 0 : (xx > 63 ? 63 : xx);
          s = fmaf(wv[dil - 1][uu * 3 + vv], t[yy][xx], s);
        }
    ov[j] = bf16rne(fmaf(s, cs_reg[j], x_reg[j] * Dv));
  }
  ushort8_t o0, o1;
#pragma unroll
  for (int j = 0; j < 8; ++j) { o0[j] = ov[j]; o1[j] = ov[8 + j]; }
  *(ushort8_t*)&ypre[base + l0]     = o0;
  *(ushort8_t*)&ypre[base + l0 + 8] = o1;
}

// ---------------- bf16 transpose (B,D,L) -> (B,L,D) --------------------------
__global__ __launch_bounds__(256)
void transpose_bf16_k(const unsigned short* __restrict__ src,
                      unsigned short* __restrict__ dst)
{
  __shared__ unsigned short t[64][72];   // [l][d], pad 72
  int l0 = blockIdx.x * 64;
  int d0 = blockIdx.y * 64;
  int b  = blockIdx.z;
  int tid = threadIdx.x;
  int dl = tid & 63, lg0 = tid >> 6;
#pragma unroll
  for (int i = 0; i < 2; ++i) {
    int lg = lg0 + i * 4;                // l-chunk of 8
    ushort8_t v = *(const ushort8_t*)&src[(size_t)(b * 512 + d0 + dl) * 4096 + l0 + lg * 8];
#pragma unroll
    for (int j = 0; j < 8; ++j) t[lg * 8 + j][dl] = v[j];
  }
  __syncthreads();
  int pl = tid >> 2, c0 = (tid & 3) << 4;
  ushort8_t a = *(const ushort8_t*)&t[pl][c0];
  ushort8_t bb = *(const ushort8_t*)&t[pl][c0 + 8];
  size_t o = (size_t)(b * 4096 + l0 + pl) * 512 + d0 + c0;
  *(ushort8_t*)&dst[o] = a;
  *(ushort8_t*)&dst[o + 8] = bb;
}

// -------- LayerNorm over D + silu(z) gate, bf16 in/out ----------------------
__global__ __launch_bounds__(256)
void ln_silu_split_k(const unsigned short* __restrict__ y,
                     const unsigned short* __restrict__ z,
                     const float* __restrict__ lw, const float* __restrict__ lb,
                     unsigned short* __restrict__ hi)
{
  int wid = threadIdx.x >> 6, lane = threadIdx.x & 63;
  int pix = blockIdx.x * 4 + wid;            // 0..16383
  const unsigned short* yp = y + (size_t)pix * 512;
  const unsigned short* zp = z + (size_t)pix * 512;
  ushort8_t yv8 = *(const ushort8_t*)&yp[lane * 8];
  float vv[8];
#pragma unroll
  for (int j = 0; j < 8; j++) vv[j] = b2f(yv8[j]);
  float sum = 0.f;
#pragma unroll
  for (int j = 0; j < 8; j++) sum += vv[j];
#pragma unroll
  for (int off = 1; off < 64; off <<= 1) sum += __shfl_xor(sum, off);
  float mu = sum * (1.f / 512.f);
  float q = 0.f;
#pragma unroll
  for (int j = 0; j < 8; j++) { float dd = vv[j] - mu; q += dd * dd; }
#pragma unroll
  for (int off = 1; off < 64; off <<= 1) q += __shfl_xor(q, off);
  float rstd = rsqrtf(q * (1.f / 512.f) + 1e-5f);
  ushort8_t zv8 = *(const ushort8_t*)&zp[lane * 8];
  unsigned short oh[8];
#pragma unroll
  for (int j = 0; j < 8; j++) {
    int dch = lane * 8 + j;
    float val = (vv[j] - mu) * rstd * lw[dch] + lb[dch];
    float zv = b2f(zv8[j]);
    float ov = val * (zv * (1.f / (1.f + __expf(-zv))));
    oh[j] = bf16rne(ov);
  }
  size_t o = (size_t)pix * 512 + lane * 8;
  *(ushort4*)&hi[o]     = make_ushort4(oh[0], oh[1], oh[2], oh[3]);
  *(ushort4*)&hi[o + 4] = make_ushort4(oh[4], oh[5], oh[6], oh[7]);
}

extern "C" void kernel_launch(void* const* d_in, const int* in_sizes, int n_in,
                              void* d_out, int out_size, void* d_ws, size_t ws_size,
                              hipStream_t stream)
{
  const float* x    = (const float*)d_in[0];
  const float* win  = (const float*)d_in[1];
  const float* cw   = (const float*)d_in[2];
  const float* cb   = (const float*)d_in[3];
  const float* xpw  = (const float*)d_in[4];
  const float* dtw  = (const float*)d_in[5];
  const float* dtb  = (const float*)d_in[6];
  const float* alog = (const float*)d_in[7];
  const float* Dsv  = (const float*)d_in[8];
  const float* k1   = (const float*)d_in[9];
  const float* k2   = (const float*)d_in[10];
  const float* k3   = (const float*)d_in[11];
  const float* alp  = (const float*)d_in[12];
  const float* lw   = (const float*)d_in[13];
  const float* lb   = (const float*)d_in[14];
  const float* wout = (const float*)d_in[15];
  float* out = (float*)d_out;

  const size_t NP = (size_t)4 * 512 * 4096;   // 8,388,608 elems per (B,D,L) buffer
  float* ws = (float*)d_ws;
  float* xs     = ws;                 // Whi -> xs fp32 -> y_t bf16 -> Ohi
  float* zbuf   = ws + NP;            // z bf16 (1st half) | ypre bf16 (2nd half)
  float* w4     = ws + 2 * NP;        // Ahi -> delta -> Yhi
  float* xdbl_r = ws + 3 * NP;        // 34 x 16384

  unsigned short* Ahi  = (unsigned short*)w4;        // 16384x512 bf16
  unsigned short* Whi  = (unsigned short*)xs;        // 1024x512 bf16
  unsigned short* xinb = (unsigned short*)d_out;     // xin bf16 (d_out scratch)
  unsigned short* zb16 = (unsigned short*)zbuf;              // 16384x512 bf16
  unsigned short* yp16 = zb16 + (size_t)16384 * 512;         // ypre bf16
  unsigned short* yt16 = (unsigned short*)xs;        // y_t bf16 (xs dead)
  unsigned short* Yhi  = (unsigned short*)w4;        // after delta consumed
  unsigned short* Ohi  = (unsigned short*)xs;        // after y_t consumed
  float* xsf = xs;                                   // xs fp32 view

  prep_k<<<8704, 256, 0, stream>>>(x, win, Ahi, Whi);                       // x, win -> bf16
  gemm0_k<<<1024, 256, 0, stream>>>(Ahi, Whi, xinb, zb16);                  // xin, z (bf16)
  conv_silu_k<<<2048, 256, 0, stream>>>(xinb, cw, cb, xsf);                 // xs fp32
  xdbl_part_k<<<dim3(64, 8), 256, 0, stream>>>(xsf, xpw, out);              // partial->d_out
  xdbl_reduce_k<<<2176, 256, 0, stream>>>(out, xdbl_r);                     // xdbl_r
  delta_k<<<dim3(16, 8, 4), 256, 0, stream>>>(xdbl_r, dtw, dtb, w4);        // delta->w4
  scan_sfconv_k<<<2048, 256, 0, stream>>>(w4, xdbl_r + 32 * 16384, xsf, alog,
                                          k1, k2, k3, alp,
                                          xdbl_r + 33 * 16384, Dsv, yp16);  // ypre bf16
  transpose_bf16_k<<<dim3(64, 8, 4), 256, 0, stream>>>(yp16, yt16);         // y_t bf16
  ln_silu_split_k<<<4096, 256, 0, stream>>>(yt16, zb16, lw, lb, Yhi);       // y -> bf16
  cvt_hi_k<<<256, 256, 0, stream>>>(wout, Ohi, 65536);                      // wout -> bf16
  gemm1_k<<<512, 256, 0, stream>>>(Yhi, Ohi, out);                          // final 1-term
}